// Round 4
// baseline (819.814 us; speedup 1.0000x reference)
//
#include <hip/hip_runtime.h>
#include <stdint.h>

#define NUM_LEVELS 16
#define LEVEL_DIM 2
#define BASE_RES 16
#define LOG2_T 19
#define TABLE_SIZE (1u << LOG2_T)
#define TABLE_MASK (TABLE_SIZE - 1u)

#define CPL 256      // chunk-blocks per level (8*CPL = 2048 = resident-block capacity)
#define BLOCK 256

typedef float v2f __attribute__((ext_vector_type(2)));
typedef float v4f __attribute__((ext_vector_type(4)));

// Compute one point's interpolated embedding for one level.
// Table gathers are NON-TEMPORAL: random 8B accesses into a 4MB table get
// ~0 L1 hits; bypassing L1 avoids the 128B line fill from L2 per gather
// (theory: halves L2-side traffic, which is the binding constraint).
__device__ __forceinline__ v2f encode_point(
    const float* __restrict__ x, const float* __restrict__ tb,
    int n, float res, uint32_t lv)
{
    float px = __builtin_nontemporal_load(x + (size_t)n * 3 + 0);
    float py = __builtin_nontemporal_load(x + (size_t)n * 3 + 1);
    float pz = __builtin_nontemporal_load(x + (size_t)n * 3 + 2);

    px = fminf(fmaxf((px + 1.0f) * 0.5f, 0.0f), 1.0f - 1e-6f);
    py = fminf(fmaxf((py + 1.0f) * 0.5f, 0.0f), 1.0f - 1e-6f);
    pz = fminf(fmaxf((pz + 1.0f) * 0.5f, 0.0f), 1.0f - 1e-6f);

    float sx = px * res, sy = py * res, sz = pz * res;
    float fx = floorf(sx), fy = floorf(sy), fz = floorf(sz);
    float tx = sx - fx, ty = sy - fy, tz = sz - fz;
    uint32_t ix = (uint32_t)(int32_t)fx;
    uint32_t iy = (uint32_t)(int32_t)fy;
    uint32_t iz = (uint32_t)(int32_t)fz;

    uint32_t hx0 = ix;
    uint32_t hx1 = ix + 1u;
    uint32_t hy0 = iy * 2654435761u;
    uint32_t hy1 = (iy + 1u) * 2654435761u;
    uint32_t hz0 = iz * 805459861u;
    uint32_t hz1 = (iz + 1u) * 805459861u;

    uint32_t idx0 = ((hx0 ^ hy0 ^ hz0 ^ lv) & TABLE_MASK) * 2u;
    uint32_t idx1 = ((hx0 ^ hy0 ^ hz1 ^ lv) & TABLE_MASK) * 2u;
    uint32_t idx2 = ((hx0 ^ hy1 ^ hz0 ^ lv) & TABLE_MASK) * 2u;
    uint32_t idx3 = ((hx0 ^ hy1 ^ hz1 ^ lv) & TABLE_MASK) * 2u;
    uint32_t idx4 = ((hx1 ^ hy0 ^ hz0 ^ lv) & TABLE_MASK) * 2u;
    uint32_t idx5 = ((hx1 ^ hy0 ^ hz1 ^ lv) & TABLE_MASK) * 2u;
    uint32_t idx6 = ((hx1 ^ hy1 ^ hz0 ^ lv) & TABLE_MASK) * 2u;
    uint32_t idx7 = ((hx1 ^ hy1 ^ hz1 ^ lv) & TABLE_MASK) * 2u;

    v2f e0 = __builtin_nontemporal_load((const v2f*)(tb + idx0));
    v2f e1 = __builtin_nontemporal_load((const v2f*)(tb + idx1));
    v2f e2 = __builtin_nontemporal_load((const v2f*)(tb + idx2));
    v2f e3 = __builtin_nontemporal_load((const v2f*)(tb + idx3));
    v2f e4 = __builtin_nontemporal_load((const v2f*)(tb + idx4));
    v2f e5 = __builtin_nontemporal_load((const v2f*)(tb + idx5));
    v2f e6 = __builtin_nontemporal_load((const v2f*)(tb + idx6));
    v2f e7 = __builtin_nontemporal_load((const v2f*)(tb + idx7));

    float wx0 = 1.0f - tx, wx1 = tx;
    float wy0 = 1.0f - ty, wy1 = ty;
    float wz0 = 1.0f - tz, wz1 = tz;

    float w0 = wx0 * wy0 * wz0;
    float w1 = wx0 * wy0 * wz1;
    float w2 = wx0 * wy1 * wz0;
    float w3 = wx0 * wy1 * wz1;
    float w4 = wx1 * wy0 * wz0;
    float w5 = wx1 * wy0 * wz1;
    float w6 = wx1 * wy1 * wz0;
    float w7 = wx1 * wy1 * wz1;

    v2f acc;
    acc.x = e0.x * w0 + e1.x * w1 + e2.x * w2 + e3.x * w3
          + e4.x * w4 + e5.x * w5 + e6.x * w6 + e7.x * w7;
    acc.y = e0.y * w0 + e1.y * w1 + e2.y * w2 + e3.y * w3
          + e4.y * w4 + e5.y * w5 + e6.y * w6 + e7.y * w7;
    return acc;
}

// ---------------- Phase 1: level-sharded gather ----------------
// blockIdx % 8 -> XCD (dispatch round-robin). Levels 0..7 run first
// (blocks 0..2047), then 8..15; each XCD's 4MB L2 holds exactly one table.
__global__ __launch_bounds__(256, 8) void gather_level_kernel(
    const float* __restrict__ x,
    const float* __restrict__ tables,
    float* __restrict__ ws,      // [NUM_LEVELS][N] float2, level-major
    int N)
{
    int g = blockIdx.x;
    int half  = g / (8 * CPL);          // 0 or 1
    int h     = g % (8 * CPL);
    int level = (h & 7) + 8 * half;
    int chunk = h >> 3;
    int P     = (N + CPL - 1) / CPL;    // points per chunk
    int base  = chunk * P;

    const float* tb = tables + (size_t)level * TABLE_SIZE * LEVEL_DIM;
    v2f* wrow = (v2f*)ws + (size_t)level * N;
    float res = (float)(BASE_RES << level);
    uint32_t lv = (uint32_t)level;

    // 2 points per lane per iteration -> 16 outstanding gathers/wave
    for (int i = threadIdx.x; i < P; i += 2 * BLOCK) {
        int n0 = base + i;
        int n1 = base + i + BLOCK;
        bool ok0 = (n0 < N);
        bool ok1 = (i + BLOCK < P) && (n1 < N);

        if (ok0 && ok1) {
            v2f a0 = encode_point(x, tb, n0, res, lv);
            v2f a1 = encode_point(x, tb, n1, res, lv);
            __builtin_nontemporal_store(a0, wrow + n0);
            __builtin_nontemporal_store(a1, wrow + n1);
        } else if (ok0) {
            v2f a0 = encode_point(x, tb, n0, res, lv);
            __builtin_nontemporal_store(a0, wrow + n0);
        }
    }
}

// ---------------- Phase 2: [L][N][2] -> [N][L*2] transpose ----------------
// 2 points per thread via v4f loads; plain (cached) loads AND stores so the
// per-thread 16B stores merge into full 128B lines in L2 before writeback.
__global__ __launch_bounds__(256, 8) void transpose_kernel(
    const float* __restrict__ ws, float* __restrict__ out, int N)
{
    int t = blockIdx.x * blockDim.x + threadIdx.x;   // point-pair index
    int n0 = 2 * t;
    if (n0 >= N) return;

    if (n0 + 1 < N) {
        v4f v[NUM_LEVELS];
        #pragma unroll
        for (int l = 0; l < NUM_LEVELS; ++l)
            v[l] = *((const v4f*)(ws + (size_t)l * N * 2) + t);  // points n0,n0+1

        v4f* o0 = (v4f*)(out + (size_t)n0 * (NUM_LEVELS * LEVEL_DIM));
        v4f* o1 = (v4f*)(out + (size_t)(n0 + 1) * (NUM_LEVELS * LEVEL_DIM));
        #pragma unroll
        for (int i = 0; i < 8; ++i) {
            v4f a, b;
            a.x = v[2 * i].x;     a.y = v[2 * i].y;
            a.z = v[2 * i + 1].x; a.w = v[2 * i + 1].y;
            b.x = v[2 * i].z;     b.y = v[2 * i].w;
            b.z = v[2 * i + 1].z; b.w = v[2 * i + 1].w;
            o0[i] = a;
            o1[i] = b;
        }
    } else {
        // tail: single point
        v2f v[NUM_LEVELS];
        #pragma unroll
        for (int l = 0; l < NUM_LEVELS; ++l)
            v[l] = *((const v2f*)ws + (size_t)l * N + n0);
        v4f* o = (v4f*)(out + (size_t)n0 * (NUM_LEVELS * LEVEL_DIM));
        #pragma unroll
        for (int i = 0; i < 8; ++i) {
            v4f a;
            a.x = v[2 * i].x;     a.y = v[2 * i].y;
            a.z = v[2 * i + 1].x; a.w = v[2 * i + 1].y;
            o[i] = a;
        }
    }
}

// ---------------- Fallback: point-major (passing) ----------
__global__ __launch_bounds__(256) void hashenc_fallback(
    const float* __restrict__ x, const float* __restrict__ tables,
    float* __restrict__ out, int N)
{
    int n = blockIdx.x * blockDim.x + threadIdx.x;
    if (n >= N) return;
    float* op = out + (size_t)n * (NUM_LEVELS * LEVEL_DIM);
    #pragma unroll 4
    for (int l = 0; l < NUM_LEVELS; ++l) {
        const float* tb = tables + (size_t)l * TABLE_SIZE * LEVEL_DIM;
        v2f a = encode_point(x, tb, n, (float)(BASE_RES << l), (uint32_t)l);
        *(v2f*)(op + l * 2) = a;
    }
}

extern "C" void kernel_launch(void* const* d_in, const int* in_sizes, int n_in,
                              void* d_out, int out_size, void* d_ws, size_t ws_size,
                              hipStream_t stream) {
    const float* x      = (const float*)d_in[0];
    const float* tables = (const float*)d_in[1];
    float* out          = (float*)d_out;
    int N = in_sizes[0] / 3;

    size_t ws_needed = (size_t)NUM_LEVELS * N * LEVEL_DIM * sizeof(float);
    if (ws_size >= ws_needed) {
        float* ws = (float*)d_ws;
        gather_level_kernel<<<NUM_LEVELS * CPL, BLOCK, 0, stream>>>(x, tables, ws, N);
        int pairs = (N + 1) / 2;
        transpose_kernel<<<(pairs + BLOCK - 1) / BLOCK, BLOCK, 0, stream>>>(ws, out, N);
    } else {
        hashenc_fallback<<<(N + BLOCK - 1) / BLOCK, BLOCK, 0, stream>>>(x, tables, out, N);
    }
}

// Round 5
// 552.074 us; speedup vs baseline: 1.4850x; 1.4850x over previous
//
#include <hip/hip_runtime.h>
#include <stdint.h>

#define NUM_LEVELS 16
#define LEVEL_DIM 2
#define BASE_RES 16
#define LOG2_T 19
#define TABLE_SIZE (1u << LOG2_T)
#define TABLE_MASK (TABLE_SIZE - 1u)

#define BLOCK 256
#define GBLOCKS 2048   // == max co-resident blocks (256 CU x 8 blocks/CU)

typedef float v2f __attribute__((ext_vector_type(2)));
typedef float v4f __attribute__((ext_vector_type(4)));

// One level's interpolation for an already-clipped point. PLAIN (cached)
// table loads — L2 residency is the whole game (NT evicts from L2: R4
// showed FETCH 167MB->1.26GB, dur 315->675us. Never NT the tables.)
__device__ __forceinline__ v2f encode_level(
    const float* __restrict__ tb,
    float px, float py, float pz, float res, uint32_t lv)
{
    float sx = px * res, sy = py * res, sz = pz * res;
    float fx = floorf(sx), fy = floorf(sy), fz = floorf(sz);
    float tx = sx - fx, ty = sy - fy, tz = sz - fz;
    uint32_t ix = (uint32_t)(int32_t)fx;
    uint32_t iy = (uint32_t)(int32_t)fy;
    uint32_t iz = (uint32_t)(int32_t)fz;

    uint32_t hx0 = ix;
    uint32_t hx1 = ix + 1u;
    uint32_t hy0 = iy * 2654435761u;
    uint32_t hy1 = (iy + 1u) * 2654435761u;
    uint32_t hz0 = iz * 805459861u;
    uint32_t hz1 = (iz + 1u) * 805459861u;

    uint32_t idx0 = ((hx0 ^ hy0 ^ hz0 ^ lv) & TABLE_MASK) * 2u;
    uint32_t idx1 = ((hx0 ^ hy0 ^ hz1 ^ lv) & TABLE_MASK) * 2u;
    uint32_t idx2 = ((hx0 ^ hy1 ^ hz0 ^ lv) & TABLE_MASK) * 2u;
    uint32_t idx3 = ((hx0 ^ hy1 ^ hz1 ^ lv) & TABLE_MASK) * 2u;
    uint32_t idx4 = ((hx1 ^ hy0 ^ hz0 ^ lv) & TABLE_MASK) * 2u;
    uint32_t idx5 = ((hx1 ^ hy0 ^ hz1 ^ lv) & TABLE_MASK) * 2u;
    uint32_t idx6 = ((hx1 ^ hy1 ^ hz0 ^ lv) & TABLE_MASK) * 2u;
    uint32_t idx7 = ((hx1 ^ hy1 ^ hz1 ^ lv) & TABLE_MASK) * 2u;

    v2f e0 = *(const v2f*)(tb + idx0);
    v2f e1 = *(const v2f*)(tb + idx1);
    v2f e2 = *(const v2f*)(tb + idx2);
    v2f e3 = *(const v2f*)(tb + idx3);
    v2f e4 = *(const v2f*)(tb + idx4);
    v2f e5 = *(const v2f*)(tb + idx5);
    v2f e6 = *(const v2f*)(tb + idx6);
    v2f e7 = *(const v2f*)(tb + idx7);

    float wx0 = 1.0f - tx, wx1 = tx;
    float wy0 = 1.0f - ty, wy1 = ty;
    float wz0 = 1.0f - tz, wz1 = tz;

    float w0 = wx0 * wy0 * wz0;
    float w1 = wx0 * wy0 * wz1;
    float w2 = wx0 * wy1 * wz0;
    float w3 = wx0 * wy1 * wz1;
    float w4 = wx1 * wy0 * wz0;
    float w5 = wx1 * wy0 * wz1;
    float w6 = wx1 * wy1 * wz0;
    float w7 = wx1 * wy1 * wz1;

    v2f acc;
    acc.x = e0.x * w0 + e1.x * w1 + e2.x * w2 + e3.x * w3
          + e4.x * w4 + e5.x * w5 + e6.x * w6 + e7.x * w7;
    acc.y = e0.y * w0 + e1.y * w1 + e2.y * w2 + e3.y * w3
          + e4.y * w4 + e5.y * w5 + e6.y * w6 + e7.y * w7;
    return acc;
}

// ---------------- Phase 1: synchronized level sweep ----------------
// Grid = 2048 blocks = exactly the co-resident capacity. Every block holds a
// contiguous point chunk and iterates levels 0..15 in lockstep, so at any
// instant ALL XCDs work the SAME level; each XCD's 4MB L2 holds its own copy
// of that one table (cross-XCD refills come from the 256MB L3, which caches
// all 16 tables). Perfect XCD load balance, unlike level-per-XCD sharding.
// The point is loaded+clipped ONCE for all 16 levels (kills 16x x re-read).
__global__ __launch_bounds__(256, 8) void gather_sweep_kernel(
    const float* __restrict__ x,
    const float* __restrict__ tables,
    float* __restrict__ ws,      // [NUM_LEVELS][N] float2, level-major
    int N)
{
    int P = (N + GBLOCKS - 1) / GBLOCKS;
    int base = blockIdx.x * P;

    for (int i = threadIdx.x; i < P; i += BLOCK) {
        int n = base + i;
        if (n >= N) break;

        float px = __builtin_nontemporal_load(x + (size_t)n * 3 + 0);
        float py = __builtin_nontemporal_load(x + (size_t)n * 3 + 1);
        float pz = __builtin_nontemporal_load(x + (size_t)n * 3 + 2);
        px = fminf(fmaxf((px + 1.0f) * 0.5f, 0.0f), 1.0f - 1e-6f);
        py = fminf(fmaxf((py + 1.0f) * 0.5f, 0.0f), 1.0f - 1e-6f);
        pz = fminf(fmaxf((pz + 1.0f) * 0.5f, 0.0f), 1.0f - 1e-6f);

        // unroll 2: overlaps level l+1's 8 gathers with level l's consume
        // (~16-deep MLP) while keeping VGPRs under the 64-reg/8-wave cap.
        #pragma unroll 2
        for (int l = 0; l < NUM_LEVELS; ++l) {
            const float* tb = tables + (size_t)l * TABLE_SIZE * LEVEL_DIM;
            v2f acc = encode_level(tb, px, py, pz,
                                   (float)(BASE_RES << l), (uint32_t)l);
            __builtin_nontemporal_store(acc, (v2f*)ws + (size_t)l * N + n);
        }
    }
}

// ---------------- Phase 2: [L][N][2] -> [N][L*2] transpose ----------------
// NT loads (ws has no reuse); PLAIN stores so the 8 x 16B per-thread stores
// merge into full 128B lines in L2 before writeback (R2->R3 evidence).
__global__ __launch_bounds__(256) void transpose_kernel(
    const float* __restrict__ ws, float* __restrict__ out, int N)
{
    int n = blockIdx.x * blockDim.x + threadIdx.x;
    if (n >= N) return;

    v2f v[NUM_LEVELS];
    #pragma unroll
    for (int l = 0; l < NUM_LEVELS; ++l)
        v[l] = __builtin_nontemporal_load((const v2f*)ws + (size_t)l * N + n);

    v4f* o = (v4f*)(out + (size_t)n * (NUM_LEVELS * LEVEL_DIM));
    #pragma unroll
    for (int i = 0; i < 8; ++i) {
        v4f t;
        t.x = v[2 * i].x;     t.y = v[2 * i].y;
        t.z = v[2 * i + 1].x; t.w = v[2 * i + 1].y;
        o[i] = t;
    }
}

// ---------------- Fallback: point-major, direct to out ----------
__global__ __launch_bounds__(256) void hashenc_fallback(
    const float* __restrict__ x, const float* __restrict__ tables,
    float* __restrict__ out, int N)
{
    int n = blockIdx.x * blockDim.x + threadIdx.x;
    if (n >= N) return;
    float px = x[(size_t)n * 3 + 0];
    float py = x[(size_t)n * 3 + 1];
    float pz = x[(size_t)n * 3 + 2];
    px = fminf(fmaxf((px + 1.0f) * 0.5f, 0.0f), 1.0f - 1e-6f);
    py = fminf(fmaxf((py + 1.0f) * 0.5f, 0.0f), 1.0f - 1e-6f);
    pz = fminf(fmaxf((pz + 1.0f) * 0.5f, 0.0f), 1.0f - 1e-6f);
    float* op = out + (size_t)n * (NUM_LEVELS * LEVEL_DIM);
    #pragma unroll 4
    for (int l = 0; l < NUM_LEVELS; ++l) {
        const float* tb = tables + (size_t)l * TABLE_SIZE * LEVEL_DIM;
        v2f a = encode_level(tb, px, py, pz, (float)(BASE_RES << l), (uint32_t)l);
        *(v2f*)(op + l * 2) = a;
    }
}

extern "C" void kernel_launch(void* const* d_in, const int* in_sizes, int n_in,
                              void* d_out, int out_size, void* d_ws, size_t ws_size,
                              hipStream_t stream) {
    const float* x      = (const float*)d_in[0];
    const float* tables = (const float*)d_in[1];
    float* out          = (float*)d_out;
    int N = in_sizes[0] / 3;

    size_t ws_needed = (size_t)NUM_LEVELS * N * LEVEL_DIM * sizeof(float);
    if (ws_size >= ws_needed) {
        float* ws = (float*)d_ws;
        gather_sweep_kernel<<<GBLOCKS, BLOCK, 0, stream>>>(x, tables, ws, N);
        transpose_kernel<<<(N + BLOCK - 1) / BLOCK, BLOCK, 0, stream>>>(ws, out, N);
    } else {
        hashenc_fallback<<<(N + BLOCK - 1) / BLOCK, BLOCK, 0, stream>>>(x, tables, out, N);
    }
}

// Round 6
// 440.735 us; speedup vs baseline: 1.8601x; 1.2526x over previous
//
#include <hip/hip_runtime.h>
#include <stdint.h>

#define NUM_LEVELS 16
#define LEVEL_DIM 2
#define BASE_RES 16
#define LOG2_T 19
#define TABLE_SIZE (1u << LOG2_T)
#define TABLE_MASK (TABLE_SIZE - 1u)

#define CPL 256      // chunk-blocks per level (8*CPL = 2048 = resident-block capacity)
#define BLOCK 256

typedef float v2f __attribute__((ext_vector_type(2)));
typedef float v4f __attribute__((ext_vector_type(4)));

// Agent-scope (device) load: sc0=1, nt=0 -> bypasses L1 (no 128B line fill,
// which is the measured bottleneck: 0.35 gathers/clk/CU x 128B = ~45B/clk/CU
// ~= TCP fill BW ceiling) but still allocates in L2 (unlike R4's NT loads,
// which marked lines evict-first in L2 and blew FETCH 167MB -> 1.26GB).
__device__ __forceinline__ v2f ld_table8(const float* p) {
    uint64_t r = __hip_atomic_load((const uint64_t*)p,
                                   __ATOMIC_RELAXED, __HIP_MEMORY_SCOPE_AGENT);
    union { uint64_t u; v2f f; } c;
    c.u = r;
    return c.f;
}

// One point's interpolated embedding for one level.
__device__ __forceinline__ v2f encode_point(
    const float* __restrict__ x, const float* __restrict__ tb,
    int n, float res, uint32_t lv)
{
    float px = __builtin_nontemporal_load(x + (size_t)n * 3 + 0);
    float py = __builtin_nontemporal_load(x + (size_t)n * 3 + 1);
    float pz = __builtin_nontemporal_load(x + (size_t)n * 3 + 2);

    px = fminf(fmaxf((px + 1.0f) * 0.5f, 0.0f), 1.0f - 1e-6f);
    py = fminf(fmaxf((py + 1.0f) * 0.5f, 0.0f), 1.0f - 1e-6f);
    pz = fminf(fmaxf((pz + 1.0f) * 0.5f, 0.0f), 1.0f - 1e-6f);

    float sx = px * res, sy = py * res, sz = pz * res;
    float fx = floorf(sx), fy = floorf(sy), fz = floorf(sz);
    float tx = sx - fx, ty = sy - fy, tz = sz - fz;
    uint32_t ix = (uint32_t)(int32_t)fx;
    uint32_t iy = (uint32_t)(int32_t)fy;
    uint32_t iz = (uint32_t)(int32_t)fz;

    uint32_t hx0 = ix;
    uint32_t hx1 = ix + 1u;
    uint32_t hy0 = iy * 2654435761u;
    uint32_t hy1 = (iy + 1u) * 2654435761u;
    uint32_t hz0 = iz * 805459861u;
    uint32_t hz1 = (iz + 1u) * 805459861u;

    uint32_t idx0 = ((hx0 ^ hy0 ^ hz0 ^ lv) & TABLE_MASK) * 2u;
    uint32_t idx1 = ((hx0 ^ hy0 ^ hz1 ^ lv) & TABLE_MASK) * 2u;
    uint32_t idx2 = ((hx0 ^ hy1 ^ hz0 ^ lv) & TABLE_MASK) * 2u;
    uint32_t idx3 = ((hx0 ^ hy1 ^ hz1 ^ lv) & TABLE_MASK) * 2u;
    uint32_t idx4 = ((hx1 ^ hy0 ^ hz0 ^ lv) & TABLE_MASK) * 2u;
    uint32_t idx5 = ((hx1 ^ hy0 ^ hz1 ^ lv) & TABLE_MASK) * 2u;
    uint32_t idx6 = ((hx1 ^ hy1 ^ hz0 ^ lv) & TABLE_MASK) * 2u;
    uint32_t idx7 = ((hx1 ^ hy1 ^ hz1 ^ lv) & TABLE_MASK) * 2u;

    v2f e0 = ld_table8(tb + idx0);
    v2f e1 = ld_table8(tb + idx1);
    v2f e2 = ld_table8(tb + idx2);
    v2f e3 = ld_table8(tb + idx3);
    v2f e4 = ld_table8(tb + idx4);
    v2f e5 = ld_table8(tb + idx5);
    v2f e6 = ld_table8(tb + idx6);
    v2f e7 = ld_table8(tb + idx7);

    float wx0 = 1.0f - tx, wx1 = tx;
    float wy0 = 1.0f - ty, wy1 = ty;
    float wz0 = 1.0f - tz, wz1 = tz;

    float w0 = wx0 * wy0 * wz0;
    float w1 = wx0 * wy0 * wz1;
    float w2 = wx0 * wy1 * wz0;
    float w3 = wx0 * wy1 * wz1;
    float w4 = wx1 * wy0 * wz0;
    float w5 = wx1 * wy0 * wz1;
    float w6 = wx1 * wy1 * wz0;
    float w7 = wx1 * wy1 * wz1;

    v2f acc;
    acc.x = e0.x * w0 + e1.x * w1 + e2.x * w2 + e3.x * w3
          + e4.x * w4 + e5.x * w5 + e6.x * w6 + e7.x * w7;
    acc.y = e0.y * w0 + e1.y * w1 + e2.y * w2 + e3.y * w3
          + e4.y * w4 + e5.y * w5 + e6.y * w6 + e7.y * w7;
    return acc;
}

// ---------------- Phase 1: level-sharded gather (R3 structure) -------------
// blockIdx % 8 -> XCD (dispatch round-robin). Levels 0..7 run first
// (blocks 0..2047), then 8..15; each XCD's 4MB L2 holds exactly one table.
// (R5 lesson: per-point level loops destroy cross-block level coherence —
// keep level fixed per block.)
__global__ __launch_bounds__(256, 8) void gather_level_kernel(
    const float* __restrict__ x,
    const float* __restrict__ tables,
    float* __restrict__ ws,      // [NUM_LEVELS][N] float2, level-major
    int N)
{
    int g = blockIdx.x;
    int half  = g / (8 * CPL);          // 0 or 1
    int h     = g % (8 * CPL);
    int level = (h & 7) + 8 * half;
    int chunk = h >> 3;
    int P     = (N + CPL - 1) / CPL;    // points per chunk
    int base  = chunk * P;

    const float* tb = tables + (size_t)level * TABLE_SIZE * LEVEL_DIM;
    v2f* wrow = (v2f*)ws + (size_t)level * N;
    float res = (float)(BASE_RES << level);
    uint32_t lv = (uint32_t)level;

    // 2 points per lane per iteration -> 16 outstanding gathers/wave
    for (int i = threadIdx.x; i < P; i += 2 * BLOCK) {
        int n0 = base + i;
        int n1 = base + i + BLOCK;
        bool ok0 = (n0 < N);
        bool ok1 = (i + BLOCK < P) && (n1 < N);

        if (ok0 && ok1) {
            v2f a0 = encode_point(x, tb, n0, res, lv);
            v2f a1 = encode_point(x, tb, n1, res, lv);
            __builtin_nontemporal_store(a0, wrow + n0);
            __builtin_nontemporal_store(a1, wrow + n1);
        } else if (ok0) {
            v2f a0 = encode_point(x, tb, n0, res, lv);
            __builtin_nontemporal_store(a0, wrow + n0);
        }
    }
}

// ---------------- Phase 2: [L][N][2] -> [N][L*2] transpose ----------------
// NT loads (ws has no reuse); PLAIN stores so the 8 x 16B per-thread stores
// merge into full 128B lines in L2 before writeback (R2->R3 evidence; the
// R4 pair-variant regressed — keep 1 point/thread).
__global__ __launch_bounds__(256) void transpose_kernel(
    const float* __restrict__ ws, float* __restrict__ out, int N)
{
    int n = blockIdx.x * blockDim.x + threadIdx.x;
    if (n >= N) return;

    v2f v[NUM_LEVELS];
    #pragma unroll
    for (int l = 0; l < NUM_LEVELS; ++l)
        v[l] = __builtin_nontemporal_load((const v2f*)ws + (size_t)l * N + n);

    v4f* o = (v4f*)(out + (size_t)n * (NUM_LEVELS * LEVEL_DIM));
    #pragma unroll
    for (int i = 0; i < 8; ++i) {
        v4f t;
        t.x = v[2 * i].x;     t.y = v[2 * i].y;
        t.z = v[2 * i + 1].x; t.w = v[2 * i + 1].y;
        o[i] = t;
    }
}

// ---------------- Fallback: point-major, direct to out ----------
__global__ __launch_bounds__(256) void hashenc_fallback(
    const float* __restrict__ x, const float* __restrict__ tables,
    float* __restrict__ out, int N)
{
    int n = blockIdx.x * blockDim.x + threadIdx.x;
    if (n >= N) return;
    float* op = out + (size_t)n * (NUM_LEVELS * LEVEL_DIM);
    #pragma unroll 4
    for (int l = 0; l < NUM_LEVELS; ++l) {
        const float* tb = tables + (size_t)l * TABLE_SIZE * LEVEL_DIM;
        v2f a = encode_point(x, tb, n, (float)(BASE_RES << l), (uint32_t)l);
        *(v2f*)(op + l * 2) = a;
    }
}

extern "C" void kernel_launch(void* const* d_in, const int* in_sizes, int n_in,
                              void* d_out, int out_size, void* d_ws, size_t ws_size,
                              hipStream_t stream) {
    const float* x      = (const float*)d_in[0];
    const float* tables = (const float*)d_in[1];
    float* out          = (float*)d_out;
    int N = in_sizes[0] / 3;

    size_t ws_needed = (size_t)NUM_LEVELS * N * LEVEL_DIM * sizeof(float);
    if (ws_size >= ws_needed) {
        float* ws = (float*)d_ws;
        gather_level_kernel<<<NUM_LEVELS * CPL, BLOCK, 0, stream>>>(x, tables, ws, N);
        transpose_kernel<<<(N + BLOCK - 1) / BLOCK, BLOCK, 0, stream>>>(ws, out, N);
    } else {
        hashenc_fallback<<<(N + BLOCK - 1) / BLOCK, BLOCK, 0, stream>>>(x, tables, out, N);
    }
}